// Round 5
// baseline (415.349 us; speedup 1.0000x reference)
//
#include <hip/hip_runtime.h>
#include <hip/hip_bf16.h>

// Problem constants
#define TT    2048
#define DD    1024
#define NH    16
#define DH    64

typedef __attribute__((ext_vector_type(8))) short bf16x8;
typedef __attribute__((ext_vector_type(4))) float f32x4;

__device__ __forceinline__ float bf2f(unsigned short u) {
  unsigned int x = ((unsigned int)u) << 16;
  return __builtin_bit_cast(float, x);
}
__device__ __forceinline__ unsigned short f2bf(float f) {
  unsigned int x = __builtin_bit_cast(unsigned int, f);
  x = (x + 0x7fffu + ((x >> 16) & 1u)) >> 16;
  return (unsigned short)x;
}

__device__ __forceinline__ bf16x8 load8(const float* p) {
  bf16x8 r;
#pragma unroll
  for (int e = 0; e < 8; ++e) r[e] = (short)f2bf(p[e]);
  return r;
}
__device__ __forceinline__ bf16x8 load8(const unsigned short* p) {
  return *(const bf16x8*)p;
}

// ---------------------------------------------------------------------------
// C[M,N] = A[M,K] · B[N,K]^T (+bias), bf16 MFMA, fp32 accumulate.
// TA: fp32 (raw inputs) or bf16/ushort (attention ctx).
// TC: ushort (bf16 intermediates in ws) or float (final output to d_out).
// Cross-validated vs naive VALU GEMM in R3/R4 (bit-identical results).
// ---------------------------------------------------------------------------
#define TM 128
#define TN 128
#define BK 32
#define LDSK 40

template <typename TA, typename TC>
__global__ __launch_bounds__(256) void gemm_bt(
    const TA* __restrict__ A,
    const float* __restrict__ B,
    const float* __restrict__ bias,
    TC* __restrict__ C,
    int M, int N, int K)
{
  __shared__ unsigned short As[TM * LDSK];
  __shared__ unsigned short Bs[TN * LDSK];

  const int tid  = threadIdx.x;
  const int wave = tid >> 6;
  const int lane = tid & 63;
  const int lr   = lane & 15;
  const int quad = lane >> 4;
  const int bm   = blockIdx.x * TM;
  const int bn   = blockIdx.y * TN;
  const int wm   = (wave >> 1) * 64;
  const int wn   = (wave & 1) * 64;

  f32x4 acc[4][4] = {};

  for (int k0 = 0; k0 < K; k0 += BK) {
#pragma unroll
    for (int i = 0; i < 2; ++i) {
      int c   = tid + i * 256;
      int row = c >> 2;
      int col = (c & 3) * 8;
      *(bf16x8*)&As[row * LDSK + col] =
          load8(&A[(size_t)(bm + row) * K + k0 + col]);
      *(bf16x8*)&Bs[row * LDSK + col] =
          load8(&B[(size_t)(bn + row) * K + k0 + col]);
    }
    __syncthreads();

    bf16x8 af[4], bfr[4];
#pragma unroll
    for (int mt = 0; mt < 4; ++mt)
      af[mt] = *(const bf16x8*)&As[(wm + mt * 16 + lr) * LDSK + quad * 8];
#pragma unroll
    for (int nt = 0; nt < 4; ++nt)
      bfr[nt] = *(const bf16x8*)&Bs[(wn + nt * 16 + lr) * LDSK + quad * 8];

#pragma unroll
    for (int mt = 0; mt < 4; ++mt)
#pragma unroll
      for (int nt = 0; nt < 4; ++nt)
        acc[mt][nt] = __builtin_amdgcn_mfma_f32_16x16x32_bf16(
            af[mt], bfr[nt], acc[mt][nt], 0, 0, 0);
    __syncthreads();
  }

  // Epilogue: C/D layout col = lane&15, row = quad*4 + reg.
#pragma unroll
  for (int nt = 0; nt < 4; ++nt) {
    int col = bn + wn + nt * 16 + lr;
    float bv = bias ? bias[col] : 0.0f;
#pragma unroll
    for (int mt = 0; mt < 4; ++mt) {
      int row = bm + wm + mt * 16 + quad * 4;
#pragma unroll
      for (int r = 0; r < 4; ++r) {
        float v = acc[mt][nt][r] + bv;
        if constexpr (__is_same(TC, float)) {
          C[(size_t)(row + r) * N + col] = v;
        } else {
          C[(size_t)(row + r) * N + col] = f2bf(v);
        }
      }
    }
  }
}

// ---------------------------------------------------------------------------
// Flash-style causal attention (verbatim R2 — cross-validated vs naive attn
// in R3: bit-identical results). One block = (b, h, 64-row Q tile).
// ---------------------------------------------------------------------------
#define ALD 72

__global__ __launch_bounds__(256) void attn_fused(
    const unsigned short* __restrict__ Q,
    const unsigned short* __restrict__ K,
    const unsigned short* __restrict__ V,
    unsigned short* __restrict__ ctx)
{
  __shared__ unsigned short Ks[64 * ALD];
  __shared__ unsigned short Vt[64 * ALD];
  __shared__ unsigned short Ps[4 * 16 * ALD];

  const int tid  = threadIdx.x;
  const int wave = tid >> 6;
  const int lane = tid & 63;
  const int lr   = lane & 15;
  const int quad = lane >> 4;

  const int qt = blockIdx.x & 31;
  const int h  = (blockIdx.x >> 5) & 15;
  const int b  = blockIdx.x >> 9;

  const size_t base = (size_t)b * TT * DD + (size_t)h * DH;
  const int qbase = qt * 64 + wave * 16;

  bf16x8 qf[2];
#pragma unroll
  for (int kb = 0; kb < 2; ++kb)
    qf[kb] = *(const bf16x8*)&Q[base + (size_t)(qbase + lr) * DD + kb * 32 + quad * 8];

  float m_i[4], l_i[4];
#pragma unroll
  for (int r = 0; r < 4; ++r) { m_i[r] = -1e30f; l_i[r] = 0.0f; }
  f32x4 o[4] = {};

  const float LOG2E = 1.44269504f;
  const float scale = 0.125f;

  for (int j = 0; j <= qt; ++j) {
#pragma unroll
    for (int i = 0; i < 2; ++i) {
      int c   = tid + i * 256;
      int row = c >> 3;
      int col = (c & 7) * 8;
      *(bf16x8*)&Ks[row * ALD + col] =
          *(const bf16x8*)&K[base + (size_t)(j * 64 + row) * DD + col];
      bf16x8 vv = *(const bf16x8*)&V[base + (size_t)(j * 64 + row) * DD + col];
#pragma unroll
      for (int e = 0; e < 8; ++e)
        Vt[(col + e) * ALD + row] = (unsigned short)vv[e];
    }
    __syncthreads();

    f32x4 s[4] = {};
#pragma unroll
    for (int nt = 0; nt < 4; ++nt) {
#pragma unroll
      for (int kb = 0; kb < 2; ++kb) {
        bf16x8 kf = *(const bf16x8*)&Ks[(nt * 16 + lr) * ALD + kb * 32 + quad * 8];
        s[nt] = __builtin_amdgcn_mfma_f32_16x16x32_bf16(qf[kb], kf, s[nt], 0, 0, 0);
      }
    }

    const bool diag = (j == qt);
#pragma unroll
    for (int nt = 0; nt < 4; ++nt) {
#pragma unroll
      for (int r = 0; r < 4; ++r) {
        float v = s[nt][r] * scale;
        if (diag) {
          int col = j * 64 + nt * 16 + lr;
          int row = qbase + quad * 4 + r;
          if (col > row) v = -1e30f;
        }
        s[nt][r] = v;
      }
    }

    float p[4][4];
    float alpha[4];
#pragma unroll
    for (int r = 0; r < 4; ++r) {
      float mx = fmaxf(fmaxf(s[0][r], s[1][r]), fmaxf(s[2][r], s[3][r]));
#pragma unroll
      for (int off = 1; off < 16; off <<= 1)
        mx = fmaxf(mx, __shfl_xor(mx, off, 64));
      float mnew = fmaxf(m_i[r], mx);
      alpha[r] = exp2f((m_i[r] - mnew) * LOG2E);
      float rs = 0.0f;
#pragma unroll
      for (int nt = 0; nt < 4; ++nt) {
        float pv = exp2f((s[nt][r] - mnew) * LOG2E);
        p[nt][r] = pv;
        rs += pv;
      }
#pragma unroll
      for (int off = 1; off < 16; off <<= 1)
        rs += __shfl_xor(rs, off, 64);
      l_i[r] = l_i[r] * alpha[r] + rs;
      m_i[r] = mnew;
    }
#pragma unroll
    for (int nt = 0; nt < 4; ++nt)
#pragma unroll
      for (int r = 0; r < 4; ++r)
        o[nt][r] *= alpha[r];

    unsigned short* myP = &Ps[wave * 16 * ALD];
#pragma unroll
    for (int nt = 0; nt < 4; ++nt)
#pragma unroll
      for (int r = 0; r < 4; ++r)
        myP[(quad * 4 + r) * ALD + nt * 16 + lr] = f2bf(p[nt][r]);
    __syncthreads();

#pragma unroll
    for (int kb = 0; kb < 2; ++kb) {
      bf16x8 pf = *(const bf16x8*)&myP[lr * ALD + kb * 32 + quad * 8];
#pragma unroll
      for (int nt = 0; nt < 4; ++nt) {
        bf16x8 vf = *(const bf16x8*)&Vt[(nt * 16 + lr) * ALD + kb * 32 + quad * 8];
        o[nt] = __builtin_amdgcn_mfma_f32_16x16x32_bf16(pf, vf, o[nt], 0, 0, 0);
      }
    }
    __syncthreads();
  }

#pragma unroll
  for (int nt = 0; nt < 4; ++nt) {
    int col = h * DH + nt * 16 + lr;
#pragma unroll
    for (int r = 0; r < 4; ++r) {
      int row = qbase + quad * 4 + r;
      float v = o[nt][r] / l_i[r];
      ctx[(size_t)b * TT * DD + (size_t)row * DD + col] = f2bf(v);
    }
  }
}

// ---------------------------------------------------------------------------
extern "C" void kernel_launch(void* const* d_in, const int* in_sizes, int n_in,
                              void* d_out, int out_size, void* d_ws, size_t ws_size,
                              hipStream_t stream) {
  // Reference dtypes are ALL fp32: inputs fp32 (proven by R1 NaN fingerprint),
  // and therefore the output is fp32 too (R2-R4's shared bug: bf16 stores into
  // an fp32 buffer -> decorrelated read-back, absmax 4.23 = sqrt(2)*max|ref|).
  const float* x  = (const float*)d_in[0];
  const float* Wq = (const float*)d_in[1];
  const float* Wk = (const float*)d_in[2];
  const float* Wv = (const float*)d_in[3];
  const float* Wo = (const float*)d_in[4];
  const float* bo = (const float*)d_in[5];
  float* out = (float*)d_out;
  unsigned short* ws = (unsigned short*)d_ws;

  const int M = 2 * TT;   // 4096 rows
  const size_t SZ = (size_t)M * DD;

  // Reference swap: queries = x@Wk.T (-> Q), keys = x@Wq.T (-> K).
  unsigned short* Qb = ws;
  unsigned short* Kb = ws + SZ;
  unsigned short* Vb = ws + 2 * SZ;
  unsigned short* Cb = ws + 3 * SZ;

  dim3 g(M / TM, DD / TN);   // 32 x 8
  gemm_bt<float, unsigned short><<<g, 256, 0, stream>>>(x, Wk, nullptr, Qb, M, DD, DD);
  gemm_bt<float, unsigned short><<<g, 256, 0, stream>>>(x, Wq, nullptr, Kb, M, DD, DD);
  gemm_bt<float, unsigned short><<<g, 256, 0, stream>>>(x, Wv, nullptr, Vb, M, DD, DD);

  attn_fused<<<dim3(2 * NH * (TT / 64)), 256, 0, stream>>>(Qb, Kb, Vb, Cb);

  gemm_bt<unsigned short, float><<<g, 256, 0, stream>>>(Cb, Wo, bo, out, M, DD, DD);
}

// Round 6
// 292.011 us; speedup vs baseline: 1.4224x; 1.4224x over previous
//
#include <hip/hip_runtime.h>

// Problem constants
#define TT 2048
#define DD 1024
#define NH 16
#define DH 64
#define MR 4096            // B*T rows

typedef __attribute__((ext_vector_type(8))) short bf16x8;
typedef __attribute__((ext_vector_type(4))) float f32x4;

__device__ __forceinline__ float bf2f(unsigned short u) {
  unsigned int x = ((unsigned int)u) << 16;
  return __builtin_bit_cast(float, x);
}
__device__ __forceinline__ unsigned short f2bf(float f) {
  unsigned int x = __builtin_bit_cast(unsigned int, f);
  x = (x + 0x7fffu + ((x >> 16) & 1u)) >> 16;
  return (unsigned short)x;
}
__device__ __forceinline__ bf16x8 load8(const float* p) {
  bf16x8 r;
#pragma unroll
  for (int e = 0; e < 8; ++e) r[e] = (short)f2bf(p[e]);
  return r;
}

// Async global->LDS 16B/lane. lbase must be wave-uniform; HW adds lane*16.
// Fallback is semantically identical (per-lane 16B copy to lbase+lane*16).
__device__ __forceinline__ void stage16(const unsigned short* g,
                                        unsigned short* lbase, int lane) {
#if __has_builtin(__builtin_amdgcn_global_load_lds)
  __builtin_amdgcn_global_load_lds(
      (const __attribute__((address_space(1))) unsigned int*)g,
      (__attribute__((address_space(3))) unsigned int*)(lbase + lane * 8),
      16, 0, 0);
#else
  *(bf16x8*)(lbase + lane * 8) = *(const bf16x8*)g;
#endif
}

// ---------------------------------------------------------------------------
// Weight convert: Wb (bf16) rows = [Wk; Wq; Wv; Wo]  (reference Q/K swap!)
// ---------------------------------------------------------------------------
__global__ __launch_bounds__(256) void cvt_w(
    const float* __restrict__ Wq, const float* __restrict__ Wk,
    const float* __restrict__ Wv, const float* __restrict__ Wo,
    unsigned short* __restrict__ Wb)
{
  int idx = (blockIdx.x * 256 + threadIdx.x) * 8;   // 8 elems/thread
  int n = idx >> 10, col = idx & 1023;
  const float* src = (n < 1024) ? Wk + (size_t)n * 1024
                   : (n < 2048) ? Wq + (size_t)(n - 1024) * 1024
                   : (n < 3072) ? Wv + (size_t)(n - 2048) * 1024
                                : Wo + (size_t)(n - 3072) * 1024;
  *(bf16x8*)&Wb[idx] = load8(src + col);
}

// ---------------------------------------------------------------------------
// Fused QKV projection: x[4096][1024] fp32 · Wb[0:3072]^T -> Q | K | Vt.
// 128x128 tile, BK=32, XOR-swizzled unpadded LDS (conflict-free b128 frags),
// async global_load_lds for the bf16 B operand. V written TRANSPOSED to
// Vt[b][h][d][t] via an LDS-transposed epilogue (kills attn's in-loop
// transpose, R5's 2e7 bank-conflict source).
// ---------------------------------------------------------------------------
__global__ __launch_bounds__(256) void gemm_qkv(
    const float* __restrict__ x, const unsigned short* __restrict__ Wb,
    unsigned short* __restrict__ Q, unsigned short* __restrict__ Kb,
    unsigned short* __restrict__ Vt)
{
  __shared__ unsigned short pool[8704];      // As(4096) + Bs(4096) | Tt(8704)
  unsigned short* As = pool;
  unsigned short* Bs = pool + 4096;

  const int tid = threadIdx.x, wave = tid >> 6, lane = tid & 63;
  const int lr = lane & 15, quad = lane >> 4;
  const int bm = blockIdx.x * 128, bn = blockIdx.y * 128;
  const int wm = (wave >> 1) * 64, wn = (wave & 1) * 64;

  f32x4 acc[4][4] = {};

  for (int k0 = 0; k0 < 1024; k0 += 32) {
    // B: async 16B staging, swizzle phys = logical ^ ((row>>1)&3)
#pragma unroll
    for (int i = 0; i < 2; ++i) {
      int c = wave * 128 + i * 64 + lane;    // chunk 0..511
      int row = c >> 2, l8 = (c & 3) ^ ((row >> 1) & 3);
      stage16(&Wb[(size_t)(bn + row) * 1024 + k0 + l8 * 8],
              &Bs[(wave * 2 + i) * 512], lane);
    }
    // A: fp32 -> bf16 VALU staging, same swizzle
#pragma unroll
    for (int i = 0; i < 2; ++i) {
      int c = tid + i * 256;
      int row = c >> 2, l8 = c & 3, p8 = l8 ^ ((row >> 1) & 3);
      *(bf16x8*)&As[row * 32 + p8 * 8] =
          load8(&x[(size_t)(bm + row) * 1024 + k0 + l8 * 8]);
    }
    __syncthreads();

    bf16x8 af[4], bf[4];
#pragma unroll
    for (int mt = 0; mt < 4; ++mt) {
      int row = wm + mt * 16 + lr;
      af[mt] = *(const bf16x8*)&As[row * 32 + (quad ^ ((row >> 1) & 3)) * 8];
    }
#pragma unroll
    for (int nt = 0; nt < 4; ++nt) {
      int row = wn + nt * 16 + lr;
      bf[nt] = *(const bf16x8*)&Bs[row * 32 + (quad ^ ((row >> 1) & 3)) * 8];
    }
#pragma unroll
    for (int mt = 0; mt < 4; ++mt)
#pragma unroll
      for (int nt = 0; nt < 4; ++nt)
        acc[mt][nt] = __builtin_amdgcn_mfma_f32_16x16x32_bf16(
            af[mt], bf[nt], acc[mt][nt], 0, 0, 0);
    __syncthreads();
  }

  if (bn < 2048) {
    // Q or K: row-major bf16. C/D layout: col=lane&15, row=quad*4+reg.
    unsigned short* Cp = (bn < 1024) ? Q : Kb;
    int coff = (bn < 1024) ? bn : bn - 1024;
#pragma unroll
    for (int nt = 0; nt < 4; ++nt) {
      int col = coff + wn + nt * 16 + lr;
#pragma unroll
      for (int mt = 0; mt < 4; ++mt) {
        int row = bm + wm + mt * 16 + quad * 4;
#pragma unroll
        for (int r = 0; r < 4; ++r)
          Cp[(size_t)(row + r) * 1024 + col] = f2bf(acc[mt][nt][r]);
      }
    }
  } else {
    // V: transpose 128x128 tile through LDS in two 64-col halves,
    // store Vt[b][h][d][t] with coalesced 16B runs.
    const int b = bm >> 11, t0 = bm & 2047, d0 = bn - 2048;
    unsigned short* Tt = pool;               // [64][136]
#pragma unroll
    for (int hv = 0; hv < 2; ++hv) {
      __syncthreads();                       // Tt free (protects hv=0 reads too)
      if ((wave & 1) == hv) {
#pragma unroll
        for (int nt = 0; nt < 4; ++nt)
#pragma unroll
          for (int mt = 0; mt < 4; ++mt)
#pragma unroll
            for (int r = 0; r < 4; ++r)
              Tt[(nt * 16 + lr) * 136 + wm + mt * 16 + quad * 4 + r] =
                  f2bf(acc[mt][nt][r]);
      }
      __syncthreads();
#pragma unroll
      for (int ch = 0; ch < 4; ++ch) {
        int cc = tid + ch * 256;             // 0..1023
        int d64 = cc >> 4, t8 = cc & 15;
        int dg = d0 + hv * 64 + d64;
        int h = dg >> 6, d = dg & 63;
        bf16x8 v = *(const bf16x8*)&Tt[d64 * 136 + t8 * 8];
        *(bf16x8*)&Vt[(((size_t)(b * NH + h) * 64 + d) << 11) + t0 + t8 * 8] = v;
      }
    }
  }
}

// ---------------------------------------------------------------------------
// Flash attention, Bc=128. Block = (b,h,64-q-rows); wave owns 16 rows.
// K staged row-major; V staged from pre-transposed Vt (coalesced, no scalar
// LDS writes). P round-trip through wave-private LDS (no barrier needed).
// Diagonal tile: skip fully-masked half (nlim/klim). ctx aliases Q (each
// block reads exactly the Q slice it later overwrites).
// ---------------------------------------------------------------------------
#define KLD 72
#define VLD 136
#define PLD 136

__global__ __launch_bounds__(256) void attn(
    const unsigned short* __restrict__ Q,
    const unsigned short* __restrict__ Kb,
    const unsigned short* __restrict__ Vt,
    unsigned short* __restrict__ ctx)
{
  __shared__ unsigned short Ks[128 * KLD];   // [kseq][d]
  __shared__ unsigned short Vs[64 * VLD];    // [d][t]
  __shared__ unsigned short Ps[4 * 16 * PLD];

  const int tid = threadIdx.x, wave = tid >> 6, lane = tid & 63;
  const int lr = lane & 15, quad = lane >> 4;
  const int qt = blockIdx.x & 31;
  const int h  = (blockIdx.x >> 5) & 15;
  const int b  = blockIdx.x >> 9;

  const int qrow0 = qt * 64 + wave * 16;
  const size_t qbase = ((size_t)b * TT) * 1024 + h * 64;
  const size_t vbase = ((size_t)(b * NH + h) * 64) << 11;

  bf16x8 qf[2];
#pragma unroll
  for (int kb = 0; kb < 2; ++kb)
    qf[kb] = *(const bf16x8*)&Q[qbase + (size_t)(qrow0 + lr) * 1024 + kb * 32 + quad * 8];

  float m_i[4], l_i[4];
#pragma unroll
  for (int r = 0; r < 4; ++r) { m_i[r] = -1e30f; l_i[r] = 0.0f; }
  f32x4 o[4] = {};

  const float LOG2E = 1.44269504f;
  const float scale = 0.125f;
  const int jmax = qt >> 1;

  for (int j = 0; j <= jmax; ++j) {
    // stage K tile: 128 seq-rows x 64 d
#pragma unroll
    for (int i = 0; i < 4; ++i) {
      int c = tid + i * 256, row = c >> 3, c8 = c & 7;
      *(bf16x8*)&Ks[row * KLD + c8 * 8] =
          *(const bf16x8*)&Kb[qbase + (size_t)(j * 128 + row) * 1024 + c8 * 8];
    }
    // stage V tile: 64 d-rows x 128 t (already transposed in global)
#pragma unroll
    for (int i = 0; i < 4; ++i) {
      int c = tid + i * 256, d = c >> 4, t8 = c & 15;
      *(bf16x8*)&Vs[d * VLD + t8 * 8] =
          *(const bf16x8*)&Vt[vbase + ((size_t)d << 11) + j * 128 + t8 * 8];
    }
    __syncthreads();

    const bool diag = (j == jmax);
    const int nlim = (diag && !(qt & 1)) ? 4 : 8;
    const int klim = nlim >> 1;

    // S = Q K^T  (16 x 128 per wave)
    f32x4 s[8];
#pragma unroll
    for (int nt = 0; nt < 8; ++nt) s[nt] = (f32x4){0.f, 0.f, 0.f, 0.f};
#pragma unroll
    for (int nt = 0; nt < 8; ++nt)
      if (nt < nlim)
#pragma unroll
        for (int kb = 0; kb < 2; ++kb) {
          bf16x8 kf = *(const bf16x8*)&Ks[(nt * 16 + lr) * KLD + kb * 32 + quad * 8];
          s[nt] = __builtin_amdgcn_mfma_f32_16x16x32_bf16(qf[kb], kf, s[nt], 0, 0, 0);
        }

    // scale + causal mask
#pragma unroll
    for (int nt = 0; nt < 8; ++nt) {
#pragma unroll
      for (int r = 0; r < 4; ++r) {
        if (nt >= nlim) { s[nt][r] = -1e30f; continue; }
        float v = s[nt][r] * scale;
        if (diag) {
          int col = j * 128 + nt * 16 + lr;
          int row = qrow0 + quad * 4 + r;
          if (col > row) v = -1e30f;
        }
        s[nt][r] = v;
      }
    }

    // online softmax (row = quad*4+r lives in 16 lanes of the quad)
    float p[8][4], alpha[4];
#pragma unroll
    for (int r = 0; r < 4; ++r) {
      float mx = s[0][r];
#pragma unroll
      for (int nt = 1; nt < 8; ++nt) mx = fmaxf(mx, s[nt][r]);
#pragma unroll
      for (int off = 1; off < 16; off <<= 1)
        mx = fmaxf(mx, __shfl_xor(mx, off, 64));
      float mnew = fmaxf(m_i[r], mx);
      alpha[r] = exp2f((m_i[r] - mnew) * LOG2E);
      float rs = 0.0f;
#pragma unroll
      for (int nt = 0; nt < 8; ++nt) {
        float pv = exp2f((s[nt][r] - mnew) * LOG2E);
        p[nt][r] = pv;
        rs += pv;
      }
#pragma unroll
      for (int off = 1; off < 16; off <<= 1)
        rs += __shfl_xor(rs, off, 64);
      l_i[r] = l_i[r] * alpha[r] + rs;
      m_i[r] = mnew;
    }
#pragma unroll
    for (int nt = 0; nt < 4; ++nt)
#pragma unroll
      for (int r = 0; r < 4; ++r)
        o[nt][r] *= alpha[r];

    // P: C-layout -> A-layout via wave-private LDS (no barrier needed)
    unsigned short* myP = &Ps[wave * 16 * PLD];
#pragma unroll
    for (int nt = 0; nt < 8; ++nt)
      if (nt < nlim)
#pragma unroll
        for (int r = 0; r < 4; ++r)
          myP[(quad * 4 + r) * PLD + nt * 16 + lr] = f2bf(p[nt][r]);

    // O += P V
#pragma unroll
    for (int kb = 0; kb < 4; ++kb)
      if (kb < klim) {
        bf16x8 pf = *(const bf16x8*)&myP[lr * PLD + kb * 32 + quad * 8];
#pragma unroll
        for (int nt = 0; nt < 4; ++nt) {
          bf16x8 vf = *(const bf16x8*)&Vs[(nt * 16 + lr) * VLD + kb * 32 + quad * 8];
          o[nt] = __builtin_amdgcn_mfma_f32_16x16x32_bf16(pf, vf, o[nt], 0, 0, 0);
        }
      }
    __syncthreads();   // Ks/Vs rewritten next iter
  }

  // epilogue (ctx aliases Q: this block's slice was read into qf already)
#pragma unroll
  for (int nt = 0; nt < 4; ++nt) {
    int col = h * 64 + nt * 16 + lr;
#pragma unroll
    for (int r = 0; r < 4; ++r) {
      int row = qrow0 + quad * 4 + r;
      ctx[((size_t)b * TT + row) * 1024 + col] = f2bf(o[nt][r] / l_i[r]);
    }
  }
}

// ---------------------------------------------------------------------------
// Output projection: ctx(bf16) · Wo(bf16)^T + bo -> fp32. Both operands via
// async global_load_lds (m97 structure), swizzled LDS.
// ---------------------------------------------------------------------------
__global__ __launch_bounds__(256) void gemm_out(
    const unsigned short* __restrict__ A,   // ctx [4096][1024]
    const unsigned short* __restrict__ Bw,  // Wo  [1024][1024]
    const float* __restrict__ bias,
    float* __restrict__ out)
{
  __shared__ unsigned short pool[8192];
  unsigned short* As = pool;
  unsigned short* Bs = pool + 4096;

  const int tid = threadIdx.x, wave = tid >> 6, lane = tid & 63;
  const int lr = lane & 15, quad = lane >> 4;
  const int bm = blockIdx.x * 128, bn = blockIdx.y * 128;
  const int wm = (wave >> 1) * 64, wn = (wave & 1) * 64;

  f32x4 acc[4][4] = {};

  for (int k0 = 0; k0 < 1024; k0 += 32) {
#pragma unroll
    for (int i = 0; i < 2; ++i) {
      int c = wave * 128 + i * 64 + lane;
      int row = c >> 2, l8 = (c & 3) ^ ((row >> 1) & 3);
      stage16(&A[(size_t)(bm + row) * 1024 + k0 + l8 * 8],
              &As[(wave * 2 + i) * 512], lane);
      stage16(&Bw[(size_t)(bn + row) * 1024 + k0 + l8 * 8],
              &Bs[(wave * 2 + i) * 512], lane);
    }
    __syncthreads();

    bf16x8 af[4], bf[4];
#pragma unroll
    for (int mt = 0; mt < 4; ++mt) {
      int row = wm + mt * 16 + lr;
      af[mt] = *(const bf16x8*)&As[row * 32 + (quad ^ ((row >> 1) & 3)) * 8];
    }
#pragma unroll
    for (int nt = 0; nt < 4; ++nt) {
      int row = wn + nt * 16 + lr;
      bf[nt] = *(const bf16x8*)&Bs[row * 32 + (quad ^ ((row >> 1) & 3)) * 8];
    }
#pragma unroll
    for (int mt = 0; mt < 4; ++mt)
#pragma unroll
      for (int nt = 0; nt < 4; ++nt)
        acc[mt][nt] = __builtin_amdgcn_mfma_f32_16x16x32_bf16(
            af[mt], bf[nt], acc[mt][nt], 0, 0, 0);
    __syncthreads();
  }

#pragma unroll
  for (int nt = 0; nt < 4; ++nt) {
    int col = bn + wn + nt * 16 + lr;
    float bv = bias[col];
#pragma unroll
    for (int mt = 0; mt < 4; ++mt) {
      int row = bm + wm + mt * 16 + quad * 4;
#pragma unroll
      for (int r = 0; r < 4; ++r)
        out[(size_t)(row + r) * 1024 + col] = acc[mt][nt][r] + bv;
    }
  }
}

// ---------------------------------------------------------------------------
extern "C" void kernel_launch(void* const* d_in, const int* in_sizes, int n_in,
                              void* d_out, int out_size, void* d_ws, size_t ws_size,
                              hipStream_t stream) {
  const float* x  = (const float*)d_in[0];
  const float* Wq = (const float*)d_in[1];
  const float* Wk = (const float*)d_in[2];
  const float* Wv = (const float*)d_in[3];
  const float* Wo = (const float*)d_in[4];
  const float* bo = (const float*)d_in[5];
  float* out = (float*)d_out;
  unsigned short* ws = (unsigned short*)d_ws;

  const size_t SZ = (size_t)MR * DD;   // 4096*1024

  // ws layout (4 x SZ bf16 = 33.55 MB, proven budget):
  // [0] Q (later overwritten in-place by ctx)   [1] K
  // [2] Vt[b][h][d][t]                          [3] Wb = [Wk;Wq;Wv;Wo] bf16
  unsigned short* Qb  = ws;
  unsigned short* Kbf = ws + SZ;
  unsigned short* Vt  = ws + 2 * SZ;
  unsigned short* Wb  = ws + 3 * SZ;

  cvt_w<<<dim3(2048), 256, 0, stream>>>(Wq, Wk, Wv, Wo, Wb);
  gemm_qkv<<<dim3(32, 24), 256, 0, stream>>>(x, Wb, Qb, Kbf, Vt);
  attn<<<dim3(2 * NH * (TT / 64)), 256, 0, stream>>>(Qb, Kbf, Vt, Qb);
  gemm_out<<<dim3(32, 8), 256, 0, stream>>>(Qb, Wb + 3 * (size_t)DD * DD, bo, out);
}

// Round 8
// 290.286 us; speedup vs baseline: 1.4308x; 1.0059x over previous
//
#include <hip/hip_runtime.h>

// Problem constants
#define TT 2048
#define DD 1024
#define NH 16
#define DH 64
#define MR 4096            // B*T rows

typedef __attribute__((ext_vector_type(8))) short bf16x8;
typedef __attribute__((ext_vector_type(4))) short bf16x4;
typedef __attribute__((ext_vector_type(4))) float f32x4;

__device__ __forceinline__ float bf2f(unsigned short u) {
  unsigned int x = ((unsigned int)u) << 16;
  return __builtin_bit_cast(float, x);
}
__device__ __forceinline__ unsigned short f2bf(float f) {
  unsigned int x = __builtin_bit_cast(unsigned int, f);
  x = (x + 0x7fffu + ((x >> 16) & 1u)) >> 16;
  return (unsigned short)x;
}
__device__ __forceinline__ bf16x8 load8(const float* p) {
  bf16x8 r;
#pragma unroll
  for (int e = 0; e < 8; ++e) r[e] = (short)f2bf(p[e]);
  return r;
}

// K=16 bf16 MFMA (A/B = 4 bf16 in 2 VGPRs). Sᵀ C-layout == its A-layout.
#if __has_builtin(__builtin_amdgcn_mfma_f32_16x16x16_bf16)
#define MFMA_K16(A, B, C) __builtin_amdgcn_mfma_f32_16x16x16_bf16(A, B, C, 0, 0, 0)
#else
#define MFMA_K16(A, B, C) __builtin_amdgcn_mfma_f32_16x16x16bf16_1k(A, B, C, 0, 0, 0)
#endif

// Async global->LDS 16B/lane; LDS base wave-uniform, HW adds lane*16.
__device__ __forceinline__ void stage16(const unsigned short* g,
                                        unsigned short* lbase, int lane) {
#if __has_builtin(__builtin_amdgcn_global_load_lds)
  __builtin_amdgcn_global_load_lds(
      (const __attribute__((address_space(1))) unsigned int*)g,
      (__attribute__((address_space(3))) unsigned int*)(lbase + lane * 8),
      16, 0, 0);
#else
  *(bf16x8*)(lbase + lane * 8) = *(const bf16x8*)g;
#endif
}

// ---------------------------------------------------------------------------
// Convert: Wb rows = [Wk; Wq; Wv; Wo] (reference Q/K swap!); blocks >= 2048
// additionally convert x -> xb (linear). Fallback mode launches 2048 blocks.
// ---------------------------------------------------------------------------
__global__ __launch_bounds__(256) void cvt_all(
    const float* __restrict__ Wq, const float* __restrict__ Wk,
    const float* __restrict__ Wv, const float* __restrict__ Wo,
    const float* __restrict__ x,
    unsigned short* __restrict__ Wb, unsigned short* __restrict__ xb)
{
  int c = blockIdx.x * 256 + threadIdx.x;     // chunk of 8 elems
  if (c < 524288) {
    int idx = c * 8, n = idx >> 10, col = idx & 1023;
    const float* src = (n < 1024) ? Wk + (size_t)n * 1024
                     : (n < 2048) ? Wq + (size_t)(n - 1024) * 1024
                     : (n < 3072) ? Wv + (size_t)(n - 2048) * 1024
                                  : Wo + (size_t)(n - 3072) * 1024;
    *(bf16x8*)&Wb[idx] = load8(src + col);
  } else {
    size_t idx = (size_t)(c - 524288) * 8;
    *(bf16x8*)&xb[idx] = load8(&x[idx]);
  }
}

// ---------------------------------------------------------------------------
// Fused QKV projection: x[4096][1024] · Wb[0:3072]^T -> Q | K | Vt.
// 128x128 tile, BK=32, XOR-swizzled LDS, async staging for B (and A if FAST).
// V written TRANSPOSED to Vt[b][h][d][t] via LDS-transposed epilogue.
// ---------------------------------------------------------------------------
template <bool FAST>
__global__ __launch_bounds__(256) void gemm_qkv(
    const float* __restrict__ x, const unsigned short* __restrict__ xb,
    const unsigned short* __restrict__ Wb,
    unsigned short* __restrict__ Q, unsigned short* __restrict__ Kb,
    unsigned short* __restrict__ Vt)
{
  __shared__ unsigned short pool[8704];      // As(4096)+Bs(4096) | Tt(8704)
  unsigned short* As = pool;
  unsigned short* Bs = pool + 4096;

  const int tid = threadIdx.x, wave = tid >> 6, lane = tid & 63;
  const int lr = lane & 15, quad = lane >> 4;
  const int bm = blockIdx.x * 128, bn = blockIdx.y * 128;
  const int wm = (wave >> 1) * 64, wn = (wave & 1) * 64;

  f32x4 acc[4][4] = {};

  for (int k0 = 0; k0 < 1024; k0 += 32) {
#pragma unroll
    for (int i = 0; i < 2; ++i) {
      int c = wave * 128 + i * 64 + lane;    // chunk 0..511
      int row = c >> 2, l8 = (c & 3) ^ ((row >> 1) & 3);
      stage16(&Wb[(size_t)(bn + row) * 1024 + k0 + l8 * 8],
              &Bs[(wave * 2 + i) * 512], lane);
      if constexpr (FAST)
        stage16(&xb[(size_t)(bm + row) * 1024 + k0 + l8 * 8],
                &As[(wave * 2 + i) * 512], lane);
    }
    if constexpr (!FAST) {
#pragma unroll
      for (int i = 0; i < 2; ++i) {
        int c = tid + i * 256;
        int row = c >> 2, l8 = c & 3, p8 = l8 ^ ((row >> 1) & 3);
        *(bf16x8*)&As[row * 32 + p8 * 8] =
            load8(&x[(size_t)(bm + row) * 1024 + k0 + l8 * 8]);
      }
    }
    __syncthreads();

    bf16x8 af[4], bf[4];
#pragma unroll
    for (int mt = 0; mt < 4; ++mt) {
      int row = wm + mt * 16 + lr;
      af[mt] = *(const bf16x8*)&As[row * 32 + (quad ^ ((row >> 1) & 3)) * 8];
    }
#pragma unroll
    for (int nt = 0; nt < 4; ++nt) {
      int row = wn + nt * 16 + lr;
      bf[nt] = *(const bf16x8*)&Bs[row * 32 + (quad ^ ((row >> 1) & 3)) * 8];
    }
#pragma unroll
    for (int mt = 0; mt < 4; ++mt)
#pragma unroll
      for (int nt = 0; nt < 4; ++nt)
        acc[mt][nt] = __builtin_amdgcn_mfma_f32_16x16x32_bf16(
            af[mt], bf[nt], acc[mt][nt], 0, 0, 0);
    __syncthreads();
  }

  if (bn < 2048) {
    unsigned short* Cp = (bn < 1024) ? Q : Kb;
    int coff = (bn < 1024) ? bn : bn - 1024;
#pragma unroll
    for (int nt = 0; nt < 4; ++nt) {
      int col = coff + wn + nt * 16 + lr;
#pragma unroll
      for (int mt = 0; mt < 4; ++mt) {
        int row = bm + wm + mt * 16 + quad * 4;
#pragma unroll
        for (int r = 0; r < 4; ++r)
          Cp[(size_t)(row + r) * 1024 + col] = f2bf(acc[mt][nt][r]);
      }
    }
  } else {
    const int b = bm >> 11, t0 = bm & 2047, d0 = bn - 2048;
    unsigned short* Tt = pool;               // [64][136]
#pragma unroll
    for (int hv = 0; hv < 2; ++hv) {
      __syncthreads();
      if ((wave & 1) == hv) {
#pragma unroll
        for (int nt = 0; nt < 4; ++nt)
#pragma unroll
          for (int mt = 0; mt < 4; ++mt)
#pragma unroll
            for (int r = 0; r < 4; ++r)
              Tt[(nt * 16 + lr) * 136 + wm + mt * 16 + quad * 4 + r] =
                  f2bf(acc[mt][nt][r]);
      }
      __syncthreads();
#pragma unroll
      for (int ch = 0; ch < 4; ++ch) {
        int cc = tid + ch * 256;
        int d64 = cc >> 4, t8 = cc & 15;
        int dg = d0 + hv * 64 + d64;
        int h = dg >> 6, d = dg & 63;
        bf16x8 v = *(const bf16x8*)&Tt[d64 * 136 + t8 * 8];
        *(bf16x8*)&Vt[(((size_t)(b * NH + h) * 64 + d) << 11) + t0 + t8 * 8] = v;
      }
    }
  }
}

// ---------------------------------------------------------------------------
// Flash attention, Sᵀ formulation. Block = (b,h,64 q-rows); wave owns 16.
// Sᵀ = K·Qᵀ via mfma 16x16x32: C-layout col(lr)=q-row, row(quad*4+r)=k-pos.
// Softmax = per-lane register reduction + 2 cross-quad shfls; P's C-layout
// equals the K=16 MFMA A-fragment layout -> register-only pack, no LDS trip.
// Q pre-scaled by (1/8)*log2(e); softmax in base-2 domain.
// ---------------------------------------------------------------------------
#define KLD 72
#define VLD 136

__global__ __launch_bounds__(256) void attn(
    const unsigned short* __restrict__ Q,
    const unsigned short* __restrict__ Kb,
    const unsigned short* __restrict__ Vt,
    unsigned short* __restrict__ ctx)
{
  __shared__ unsigned short Ks[128 * KLD];   // [kseq][d]
  __shared__ unsigned short Vs[64 * VLD];    // [d][t]

  const int tid = threadIdx.x, wave = tid >> 6, lane = tid & 63;
  const int lr = lane & 15, quad = lane >> 4;
  const int qt = blockIdx.x & 31;
  const int h  = (blockIdx.x >> 5) & 15;
  const int b  = blockIdx.x >> 9;

  const int qrow0 = qt * 64 + wave * 16;
  const int qrow  = qrow0 + lr;              // this lane's softmax row
  const size_t qbase = ((size_t)b * TT) * 1024 + h * 64;
  const size_t vbase = ((size_t)(b * NH + h) * 64) << 11;

  // Q fragment (B-operand), pre-scaled by 0.125*log2(e)
  const float QS = 0.125f * 1.44269504f;
  bf16x8 qf[2];
#pragma unroll
  for (int kb = 0; kb < 2; ++kb) {
    bf16x8 raw = *(const bf16x8*)&Q[qbase + (size_t)(qrow0 + lr) * 1024 + kb * 32 + quad * 8];
#pragma unroll
    for (int e = 0; e < 8; ++e)
      qf[kb][e] = (short)f2bf(bf2f((unsigned short)raw[e]) * QS);
  }

  float m_i = -1e30f, l_i = 0.0f;
  f32x4 od[4] = {};                          // O[m=quad*4+r][d=dt*16+lr]
  const int jmax = qt >> 1;

  for (int j = 0; j <= jmax; ++j) {
    // stage K [128][64] row-major, V [64][128] pre-transposed
#pragma unroll
    for (int i = 0; i < 4; ++i) {
      int c = tid + i * 256, row = c >> 3, c8 = c & 7;
      *(bf16x8*)&Ks[row * KLD + c8 * 8] =
          *(const bf16x8*)&Kb[qbase + (size_t)(j * 128 + row) * 1024 + c8 * 8];
    }
#pragma unroll
    for (int i = 0; i < 4; ++i) {
      int c = tid + i * 256, d = c >> 4, t8 = c & 15;
      *(bf16x8*)&Vs[d * VLD + t8 * 8] =
          *(const bf16x8*)&Vt[vbase + ((size_t)d << 11) + j * 128 + t8 * 8];
    }
    __syncthreads();

    const bool diag = (j == jmax);
    const int nlim = (diag && !(qt & 1)) ? 4 : 8;   // skip fully-masked half

    // S^T: A = K-tile (rows=k-pos), B = Q frags (rows=q-row)
    f32x4 s[8];
#pragma unroll
    for (int nt = 0; nt < 8; ++nt)
      if (nt < nlim) {
        f32x4 a = {0.f, 0.f, 0.f, 0.f};
#pragma unroll
        for (int kb = 0; kb < 2; ++kb) {
          bf16x8 kf = *(const bf16x8*)&Ks[(nt * 16 + lr) * KLD + kb * 32 + quad * 8];
          a = __builtin_amdgcn_mfma_f32_16x16x32_bf16(kf, qf[kb], a, 0, 0, 0);
        }
        s[nt] = a;
      }

    // causal mask (diag tile only): kpos = j*128 + nt*16 + quad*4 + r
    if (diag) {
#pragma unroll
      for (int nt = 0; nt < 8; ++nt)
        if (nt < nlim)
#pragma unroll
          for (int r = 0; r < 4; ++r) {
            int kpos = j * 128 + nt * 16 + quad * 4 + r;
            if (kpos > qrow) s[nt][r] = -1e30f;
          }
    }

    // softmax: per-lane register reduction + 2 cross-quad shfls
    float mloc = -1e30f;
#pragma unroll
    for (int nt = 0; nt < 8; ++nt)
      if (nt < nlim)
#pragma unroll
        for (int r = 0; r < 4; ++r) mloc = fmaxf(mloc, s[nt][r]);
    mloc = fmaxf(mloc, __shfl_xor(mloc, 16, 64));
    mloc = fmaxf(mloc, __shfl_xor(mloc, 32, 64));
    float mnew = fmaxf(m_i, mloc);
    float alpha = exp2f(m_i - mnew);

    float rs = 0.0f;
    bf16x4 pk[8];                            // P packed as K=16 A-fragments
#pragma unroll
    for (int nt = 0; nt < 8; ++nt)
      if (nt < nlim) {
#pragma unroll
        for (int r = 0; r < 4; ++r) {
          float pv = exp2f(s[nt][r] - mnew);
          rs += pv;
          pk[nt][r] = (short)f2bf(pv);
        }
      }
    rs += __shfl_xor(rs, 16, 64);
    rs += __shfl_xor(rs, 32, 64);
    l_i = l_i * alpha + rs;
    m_i = mnew;

    // rescale O: O-rows are quad*4+r; alpha lives at lane lr==row
    float am[4];
#pragma unroll
    for (int r = 0; r < 4; ++r) am[r] = __shfl(alpha, quad * 4 + r, 16);
#pragma unroll
    for (int dt = 0; dt < 4; ++dt)
#pragma unroll
      for (int r = 0; r < 4; ++r) od[dt][r] *= am[r];

    // O += P·V  (K=16 MFMAs; B-frag from Vs[d][t])
#pragma unroll
    for (int nt = 0; nt < 8; ++nt)
      if (nt < nlim) {
#pragma unroll
        for (int dt = 0; dt < 4; ++dt) {
          bf16x4 vf = *(const bf16x4*)&Vs[(dt * 16 + lr) * VLD + nt * 16 + quad * 4];
          od[dt] = MFMA_K16(pk[nt], vf, od[dt]);
        }
      }
    __syncthreads();
  }

  // epilogue: divide by l (at lane lr==row), store (ctx aliases Q safely)
  float li[4];
#pragma unroll
  for (int r = 0; r < 4; ++r) li[r] = __shfl(l_i, quad * 4 + r, 16);
#pragma unroll
  for (int dt = 0; dt < 4; ++dt) {
    int col = h * 64 + dt * 16 + lr;
#pragma unroll
    for (int r = 0; r < 4; ++r) {
      int row = qrow0 + quad * 4 + r;
      ctx[((size_t)b * TT + row) * 1024 + col] = f2bf(od[dt][r] / li[r]);
    }
  }
}

// ---------------------------------------------------------------------------
// Output projection: ctx(bf16) · Wo(bf16)^T + bo -> fp32 out.
// ---------------------------------------------------------------------------
__global__ __launch_bounds__(256) void gemm_out(
    const unsigned short* __restrict__ A,
    const unsigned short* __restrict__ Bw,
    const float* __restrict__ bias,
    float* __restrict__ out)
{
  __shared__ unsigned short pool[8192];
  unsigned short* As = pool;
  unsigned short* Bs = pool + 4096;

  const int tid = threadIdx.x, wave = tid >> 6, lane = tid & 63;
  const int lr = lane & 15, quad = lane >> 4;
  const int bm = blockIdx.x * 128, bn = blockIdx.y * 128;
  const int wm = (wave >> 1) * 64, wn = (wave & 1) * 64;

  f32x4 acc[4][4] = {};

  for (int k0 = 0; k0 < 1024; k0 += 32) {
#pragma unroll
    for (int i = 0; i < 2; ++i) {
      int c = wave * 128 + i * 64 + lane;
      int row = c >> 2, l8 = (c & 3) ^ ((row >> 1) & 3);
      stage16(&A[(size_t)(bm + row) * 1024 + k0 + l8 * 8],
              &As[(wave * 2 + i) * 512], lane);
      stage16(&Bw[(size_t)(bn + row) * 1024 + k0 + l8 * 8],
              &Bs[(wave * 2 + i) * 512], lane);
    }
    __syncthreads();

    bf16x8 af[4], bf[4];
#pragma unroll
    for (int mt = 0; mt < 4; ++mt) {
      int row = wm + mt * 16 + lr;
      af[mt] = *(const bf16x8*)&As[row * 32 + (quad ^ ((row >> 1) & 3)) * 8];
    }
#pragma unroll
    for (int nt = 0; nt < 4; ++nt) {
      int row = wn + nt * 16 + lr;
      bf[nt] = *(const bf16x8*)&Bs[row * 32 + (quad ^ ((row >> 1) & 3)) * 8];
    }
#pragma unroll
    for (int mt = 0; mt < 4; ++mt)
#pragma unroll
      for (int nt = 0; nt < 4; ++nt)
        acc[mt][nt] = __builtin_amdgcn_mfma_f32_16x16x32_bf16(
            af[mt], bf[nt], acc[mt][nt], 0, 0, 0);
    __syncthreads();
  }

#pragma unroll
  for (int nt = 0; nt < 4; ++nt) {
    int col = bn + wn + nt * 16 + lr;
    float bv = bias[col];
#pragma unroll
    for (int mt = 0; mt < 4; ++mt) {
      int row = bm + wm + mt * 16 + quad * 4;
#pragma unroll
      for (int r = 0; r < 4; ++r)
        out[(size_t)(row + r) * 1024 + col] = acc[mt][nt][r] + bv;
    }
  }
}

// ---------------------------------------------------------------------------
extern "C" void kernel_launch(void* const* d_in, const int* in_sizes, int n_in,
                              void* d_out, int out_size, void* d_ws, size_t ws_size,
                              hipStream_t stream) {
  const float* x  = (const float*)d_in[0];
  const float* Wq = (const float*)d_in[1];
  const float* Wk = (const float*)d_in[2];
  const float* Wv = (const float*)d_in[3];
  const float* Wo = (const float*)d_in[4];
  const float* bo = (const float*)d_in[5];
  float* out = (float*)d_out;
  unsigned short* ws = (unsigned short*)d_ws;

  const size_t SZ = (size_t)MR * DD;         // 4096*1024

  // ws: [0] Q (ctx in-place)  [1] K  [2] Vt[b][h][d][t]  [3] Wb  [4] xb (opt)
  unsigned short* Qb  = ws;
  unsigned short* Kbf = ws + SZ;
  unsigned short* Vt  = ws + 2 * SZ;
  unsigned short* Wb  = ws + 3 * SZ;
  unsigned short* xb  = ws + 4 * SZ;

  const bool fast = ws_size >= 5 * SZ * sizeof(unsigned short);

  cvt_all<<<dim3(fast ? 4096 : 2048), 256, 0, stream>>>(Wq, Wk, Wv, Wo, x, Wb, xb);
  if (fast)
    gemm_qkv<true><<<dim3(32, 24), 256, 0, stream>>>(x, xb, Wb, Qb, Kbf, Vt);
  else
    gemm_qkv<false><<<dim3(32, 24), 256, 0, stream>>>(x, xb, Wb, Qb, Kbf, Vt);
  attn<<<dim3(2 * NH * (TT / 64)), 256, 0, stream>>>(Qb, Kbf, Vt, Qb);
  gemm_out<<<dim3(32, 8), 256, 0, stream>>>(Qb, Wb + 3 * (size_t)DD * DD, bo, out);
}

// Round 9
// 197.388 us; speedup vs baseline: 2.1042x; 1.4706x over previous
//
#include <hip/hip_runtime.h>

// Problem constants
#define TT 2048
#define DD 1024
#define NH 16
#define DH 64
#define MR 4096            // B*T rows

typedef __attribute__((ext_vector_type(8))) short bf16x8;
typedef __attribute__((ext_vector_type(4))) short bf16x4;
typedef __attribute__((ext_vector_type(4))) float f32x4;

__device__ __forceinline__ float bf2f(unsigned short u) {
  unsigned int x = ((unsigned int)u) << 16;
  return __builtin_bit_cast(float, x);
}
__device__ __forceinline__ unsigned short f2bf(float f) {
  unsigned int x = __builtin_bit_cast(unsigned int, f);
  x = (x + 0x7fffu + ((x >> 16) & 1u)) >> 16;
  return (unsigned short)x;
}
__device__ __forceinline__ bf16x8 load8(const float* p) {
  bf16x8 r;
#pragma unroll
  for (int e = 0; e < 8; ++e) r[e] = (short)f2bf(p[e]);
  return r;
}

// K=16 bf16 MFMA (A/B = 4 bf16 in 2 VGPRs). Sᵀ C-layout == its A-layout.
#if __has_builtin(__builtin_amdgcn_mfma_f32_16x16x16_bf16)
#define MFMA_K16(A, B, C) __builtin_amdgcn_mfma_f32_16x16x16_bf16(A, B, C, 0, 0, 0)
#else
#define MFMA_K16(A, B, C) __builtin_amdgcn_mfma_f32_16x16x16bf16_1k(A, B, C, 0, 0, 0)
#endif

// Async global->LDS 16B/lane; LDS base wave-uniform, HW adds lane*16.
__device__ __forceinline__ void stage16(const unsigned short* g,
                                        unsigned short* lbase, int lane) {
#if __has_builtin(__builtin_amdgcn_global_load_lds)
  __builtin_amdgcn_global_load_lds(
      (const __attribute__((address_space(1))) unsigned int*)g,
      (__attribute__((address_space(3))) unsigned int*)(lbase + lane * 8),
      16, 0, 0);
#else
  *(bf16x8*)(lbase + lane * 8) = *(const bf16x8*)g;
#endif
}

// ---------------------------------------------------------------------------
// Convert: Wb rows = [Wk; Wq; Wv; Wo] (reference Q/K swap!); blocks >= 2048
// additionally convert x -> xb (linear). Fallback mode launches 2048 blocks.
// ---------------------------------------------------------------------------
__global__ __launch_bounds__(256) void cvt_all(
    const float* __restrict__ Wq, const float* __restrict__ Wk,
    const float* __restrict__ Wv, const float* __restrict__ Wo,
    const float* __restrict__ x,
    unsigned short* __restrict__ Wb, unsigned short* __restrict__ xb)
{
  int c = blockIdx.x * 256 + threadIdx.x;     // chunk of 8 elems
  if (c < 524288) {
    int idx = c * 8, n = idx >> 10, col = idx & 1023;
    const float* src = (n < 1024) ? Wk + (size_t)n * 1024
                     : (n < 2048) ? Wq + (size_t)(n - 1024) * 1024
                     : (n < 3072) ? Wv + (size_t)(n - 2048) * 1024
                                  : Wo + (size_t)(n - 3072) * 1024;
    *(bf16x8*)&Wb[idx] = load8(src + col);
  } else {
    size_t idx = (size_t)(c - 524288) * 8;
    *(bf16x8*)&xb[idx] = load8(&x[idx]);
  }
}

// ---------------------------------------------------------------------------
// Fused QKV projection: x[4096][1024] · Wb[0:3072]^T -> Q | K | Vt.
// 128x128 tile, BK=32, XOR-swizzled LDS, async staging for B (and A if FAST).
// V written TRANSPOSED to Vt[b][h][d][t] via LDS-transposed epilogue.
// ---------------------------------------------------------------------------
template <bool FAST>
__global__ __launch_bounds__(256) void gemm_qkv(
    const float* __restrict__ x, const unsigned short* __restrict__ xb,
    const unsigned short* __restrict__ Wb,
    unsigned short* __restrict__ Q, unsigned short* __restrict__ Kb,
    unsigned short* __restrict__ Vt)
{
  __shared__ unsigned short pool[8704];      // As(4096)+Bs(4096) | Tt(8704)
  unsigned short* As = pool;
  unsigned short* Bs = pool + 4096;

  const int tid = threadIdx.x, wave = tid >> 6, lane = tid & 63;
  const int lr = lane & 15, quad = lane >> 4;
  const int bm = blockIdx.x * 128, bn = blockIdx.y * 128;
  const int wm = (wave >> 1) * 64, wn = (wave & 1) * 64;

  f32x4 acc[4][4] = {};

  for (int k0 = 0; k0 < 1024; k0 += 32) {
#pragma unroll
    for (int i = 0; i < 2; ++i) {
      int c = wave * 128 + i * 64 + lane;    // chunk 0..511
      int row = c >> 2, l8 = (c & 3) ^ ((row >> 1) & 3);
      stage16(&Wb[(size_t)(bn + row) * 1024 + k0 + l8 * 8],
              &Bs[(wave * 2 + i) * 512], lane);
      if constexpr (FAST)
        stage16(&xb[(size_t)(bm + row) * 1024 + k0 + l8 * 8],
                &As[(wave * 2 + i) * 512], lane);
    }
    if constexpr (!FAST) {
#pragma unroll
      for (int i = 0; i < 2; ++i) {
        int c = tid + i * 256;
        int row = c >> 2, l8 = c & 3, p8 = l8 ^ ((row >> 1) & 3);
        *(bf16x8*)&As[row * 32 + p8 * 8] =
            load8(&x[(size_t)(bm + row) * 1024 + k0 + l8 * 8]);
      }
    }
    __syncthreads();

    bf16x8 af[4], bf[4];
#pragma unroll
    for (int mt = 0; mt < 4; ++mt) {
      int row = wm + mt * 16 + lr;
      af[mt] = *(const bf16x8*)&As[row * 32 + (quad ^ ((row >> 1) & 3)) * 8];
    }
#pragma unroll
    for (int nt = 0; nt < 4; ++nt) {
      int row = wn + nt * 16 + lr;
      bf[nt] = *(const bf16x8*)&Bs[row * 32 + (quad ^ ((row >> 1) & 3)) * 8];
    }
#pragma unroll
    for (int mt = 0; mt < 4; ++mt)
#pragma unroll
      for (int nt = 0; nt < 4; ++nt)
        acc[mt][nt] = __builtin_amdgcn_mfma_f32_16x16x32_bf16(
            af[mt], bf[nt], acc[mt][nt], 0, 0, 0);
    __syncthreads();
  }

  if (bn < 2048) {
    unsigned short* Cp = (bn < 1024) ? Q : Kb;
    int coff = (bn < 1024) ? bn : bn - 1024;
#pragma unroll
    for (int nt = 0; nt < 4; ++nt) {
      int col = coff + wn + nt * 16 + lr;
#pragma unroll
      for (int mt = 0; mt < 4; ++mt) {
        int row = bm + wm + mt * 16 + quad * 4;
#pragma unroll
        for (int r = 0; r < 4; ++r)
          Cp[(size_t)(row + r) * 1024 + col] = f2bf(acc[mt][nt][r]);
      }
    }
  } else {
    const int b = bm >> 11, t0 = bm & 2047, d0 = bn - 2048;
    unsigned short* Tt = pool;               // [64][136]
#pragma unroll
    for (int hv = 0; hv < 2; ++hv) {
      __syncthreads();
      if ((wave & 1) == hv) {
#pragma unroll
        for (int nt = 0; nt < 4; ++nt)
#pragma unroll
          for (int mt = 0; mt < 4; ++mt)
#pragma unroll
            for (int r = 0; r < 4; ++r)
              Tt[(nt * 16 + lr) * 136 + wm + mt * 16 + quad * 4 + r] =
                  f2bf(acc[mt][nt][r]);
      }
      __syncthreads();
#pragma unroll
      for (int ch = 0; ch < 4; ++ch) {
        int cc = tid + ch * 256;
        int d64 = cc >> 4, t8 = cc & 15;
        int dg = d0 + hv * 64 + d64;
        int h = dg >> 6, d = dg & 63;
        bf16x8 v = *(const bf16x8*)&Tt[d64 * 136 + t8 * 8];
        *(bf16x8*)&Vt[(((size_t)(b * NH + h) * 64 + d) << 11) + t0 + t8 * 8] = v;
      }
    }
  }
}

// ---------------------------------------------------------------------------
// Flash attention v3: Sᵀ formulation + complementary tile pairing + async
// swizzled staging.
// Block p handles q-tiles (31-p) then (p): uniform 17 j-iters per block
// (fixes the R8 load imbalance: same-qt blocks piled on the same CU).
// LDS unpadded; chunk swizzle logical = phys ^ (row & mask) makes async
// staging writes conflict-free AND fragment reads <=2-way.
// ---------------------------------------------------------------------------
__global__ __launch_bounds__(256) void attn(
    const unsigned short* __restrict__ Q,
    const unsigned short* __restrict__ Kb,
    const unsigned short* __restrict__ Vt,
    unsigned short* __restrict__ ctx)
{
  __shared__ unsigned short Ks[128 * 64];    // [kseq][d]   8 chunks/row
  __shared__ unsigned short Vs[64 * 128];    // [d][t]     16 chunks/row

  const int tid = threadIdx.x, wave = tid >> 6, lane = tid & 63;
  const int lr = lane & 15, quad = lane >> 4;
  const int p = blockIdx.x & 15;
  const int h = (blockIdx.x >> 4) & 15;
  const int b = blockIdx.x >> 8;

  const size_t qkbase = ((size_t)b * TT) * 1024 + h * 64;
  const size_t vbase  = ((size_t)(b * NH + h) * 64) << 11;
  const float QS = 0.125f * 1.44269504f;     // scale * log2(e)

#pragma unroll
  for (int pass = 0; pass < 2; ++pass) {
    const int qt = pass ? p : (31 - p);
    const int qrow0 = qt * 64 + wave * 16;
    const int qrow  = qrow0 + lr;

    // Q fragment (B-operand), pre-scaled
    bf16x8 qf[2];
#pragma unroll
    for (int kb = 0; kb < 2; ++kb) {
      bf16x8 raw = *(const bf16x8*)&Q[qkbase + (size_t)(qrow0 + lr) * 1024 + kb * 32 + quad * 8];
#pragma unroll
      for (int e = 0; e < 8; ++e)
        qf[kb][e] = (short)f2bf(bf2f((unsigned short)raw[e]) * QS);
    }

    float m_i = -1e30f, l_i = 0.0f;
    f32x4 od[4] = {};                        // O[m=quad*4+r][d=dt*16+lr]
    const int jmax = qt >> 1;

    for (int j = 0; j <= jmax; ++j) {
      // async stage K [128][64]: wave stages 4 x 1KB, source-swizzled
#pragma unroll
      for (int i = 0; i < 4; ++i) {
        int ci = (wave * 4 + i) * 64 + lane;       // phys chunk 0..1023
        int row = ci >> 3, lc = (ci & 7) ^ (row & 7);
        stage16(&Kb[qkbase + (size_t)(j * 128 + row) * 1024 + lc * 8],
                &Ks[(wave * 4 + i) * 512], lane);
      }
      // async stage V [64][128] from pre-transposed Vt
#pragma unroll
      for (int i = 0; i < 4; ++i) {
        int ci = (wave * 4 + i) * 64 + lane;
        int d = ci >> 4, lc = (ci & 15) ^ (d & 15);
        stage16(&Vt[vbase + ((size_t)d << 11) + j * 128 + lc * 8],
                &Vs[(wave * 4 + i) * 512], lane);
      }
      __syncthreads();

      const bool diag = (j == jmax);
      const int nlim = (diag && !(qt & 1)) ? 4 : 8;  // skip fully-masked half

      // S^T = K·Qᵀ: C col(lr)=q-row, row(quad*4+r)=k-pos
      f32x4 s[8];
#pragma unroll
      for (int nt = 0; nt < 8; ++nt)
        if (nt < nlim) {
          f32x4 a = {0.f, 0.f, 0.f, 0.f};
#pragma unroll
          for (int kb = 0; kb < 2; ++kb) {
            int pc = (kb * 4 + quad) ^ (lr & 7);
            bf16x8 kf = *(const bf16x8*)&Ks[(nt * 16 + lr) * 64 + pc * 8];
            a = __builtin_amdgcn_mfma_f32_16x16x32_bf16(kf, qf[kb], a, 0, 0, 0);
          }
          s[nt] = a;
        }

      // causal mask (diag tile only)
      if (diag) {
#pragma unroll
        for (int nt = 0; nt < 8; ++nt)
          if (nt < nlim)
#pragma unroll
            for (int r = 0; r < 4; ++r) {
              int kpos = j * 128 + nt * 16 + quad * 4 + r;
              if (kpos > qrow) s[nt][r] = -1e30f;
            }
      }

      // softmax: per-lane register reduction + 2 cross-quad shfls
      float mloc = -1e30f;
#pragma unroll
      for (int nt = 0; nt < 8; ++nt)
        if (nt < nlim)
#pragma unroll
          for (int r = 0; r < 4; ++r) mloc = fmaxf(mloc, s[nt][r]);
      mloc = fmaxf(mloc, __shfl_xor(mloc, 16, 64));
      mloc = fmaxf(mloc, __shfl_xor(mloc, 32, 64));
      float mnew = fmaxf(m_i, mloc);
      float alpha = exp2f(m_i - mnew);

      float rs = 0.0f;
      bf16x4 pk[8];                          // P packed as K=16 A-fragments
#pragma unroll
      for (int nt = 0; nt < 8; ++nt)
        if (nt < nlim) {
#pragma unroll
          for (int r = 0; r < 4; ++r) {
            float pv = exp2f(s[nt][r] - mnew);
            rs += pv;
            pk[nt][r] = (short)f2bf(pv);
          }
        }
      rs += __shfl_xor(rs, 16, 64);
      rs += __shfl_xor(rs, 32, 64);
      l_i = l_i * alpha + rs;
      m_i = mnew;

      // rescale O: alpha for row quad*4+r lives at lane lr==row
      float am[4];
#pragma unroll
      for (int r = 0; r < 4; ++r) am[r] = __shfl(alpha, quad * 4 + r, 16);
#pragma unroll
      for (int dt = 0; dt < 4; ++dt)
#pragma unroll
        for (int r = 0; r < 4; ++r) od[dt][r] *= am[r];

      // O += P·V (K=16 MFMAs; B-frag 8B from swizzled Vs)
#pragma unroll
      for (int nt = 0; nt < 8; ++nt)
        if (nt < nlim) {
#pragma unroll
          for (int dt = 0; dt < 4; ++dt) {
            int pc = (nt * 2 + (quad >> 1)) ^ lr;
            bf16x4 vf = *(const bf16x4*)&Vs[(dt * 16 + lr) * 128 + pc * 8 + (quad & 1) * 4];
            od[dt] = MFMA_K16(pk[nt], vf, od[dt]);
          }
        }
      __syncthreads();   // Ks/Vs rewritten next iter (or next pass)
    }

    // epilogue: divide by l (at lane lr==row), store (ctx aliases Q safely:
    // this block's Q slice was loaded into qf before any store)
    float li[4];
#pragma unroll
    for (int r = 0; r < 4; ++r) li[r] = __shfl(l_i, quad * 4 + r, 16);
#pragma unroll
    for (int dt = 0; dt < 4; ++dt) {
      int col = h * 64 + dt * 16 + lr;
#pragma unroll
      for (int r = 0; r < 4; ++r) {
        int row = qrow0 + quad * 4 + r;
        ctx[((size_t)b * TT + row) * 1024 + col] = f2bf(od[dt][r] / li[r]);
      }
    }
  }
}

// ---------------------------------------------------------------------------
// Output projection: ctx(bf16) · Wo(bf16)^T + bo -> fp32 out.
// ---------------------------------------------------------------------------
__global__ __launch_bounds__(256) void gemm_out(
    const unsigned short* __restrict__ A,
    const unsigned short* __restrict__ Bw,
    const float* __restrict__ bias,
    float* __restrict__ out)
{
  __shared__ unsigned short pool[8192];
  unsigned short* As = pool;
  unsigned short* Bs = pool + 4096;

  const int tid = threadIdx.x, wave = tid >> 6, lane = tid & 63;
  const int lr = lane & 15, quad = lane >> 4;
  const int bm = blockIdx.x * 128, bn = blockIdx.y * 128;
  const int wm = (wave >> 1) * 64, wn = (wave & 1) * 64;

  f32x4 acc[4][4] = {};

  for (int k0 = 0; k0 < 1024; k0 += 32) {
#pragma unroll
    for (int i = 0; i < 2; ++i) {
      int c = wave * 128 + i * 64 + lane;
      int row = c >> 2, l8 = (c & 3) ^ ((row >> 1) & 3);
      stage16(&A[(size_t)(bm + row) * 1024 + k0 + l8 * 8],
              &As[(wave * 2 + i) * 512], lane);
      stage16(&Bw[(size_t)(bn + row) * 1024 + k0 + l8 * 8],
              &Bs[(wave * 2 + i) * 512], lane);
    }
    __syncthreads();

    bf16x8 af[4], bf[4];
#pragma unroll
    for (int mt = 0; mt < 4; ++mt) {
      int row = wm + mt * 16 + lr;
      af[mt] = *(const bf16x8*)&As[row * 32 + (quad ^ ((row >> 1) & 3)) * 8];
    }
#pragma unroll
    for (int nt = 0; nt < 4; ++nt) {
      int row = wn + nt * 16 + lr;
      bf[nt] = *(const bf16x8*)&Bs[row * 32 + (quad ^ ((row >> 1) & 3)) * 8];
    }
#pragma unroll
    for (int mt = 0; mt < 4; ++mt)
#pragma unroll
      for (int nt = 0; nt < 4; ++nt)
        acc[mt][nt] = __builtin_amdgcn_mfma_f32_16x16x32_bf16(
            af[mt], bf[nt], acc[mt][nt], 0, 0, 0);
    __syncthreads();
  }

#pragma unroll
  for (int nt = 0; nt < 4; ++nt) {
    int col = bn + wn + nt * 16 + lr;
    float bv = bias[col];
#pragma unroll
    for (int mt = 0; mt < 4; ++mt) {
      int row = bm + wm + mt * 16 + quad * 4;
#pragma unroll
      for (int r = 0; r < 4; ++r)
        out[(size_t)(row + r) * 1024 + col] = acc[mt][nt][r] + bv;
    }
  }
}

// ---------------------------------------------------------------------------
extern "C" void kernel_launch(void* const* d_in, const int* in_sizes, int n_in,
                              void* d_out, int out_size, void* d_ws, size_t ws_size,
                              hipStream_t stream) {
  const float* x  = (const float*)d_in[0];
  const float* Wq = (const float*)d_in[1];
  const float* Wk = (const float*)d_in[2];
  const float* Wv = (const float*)d_in[3];
  const float* Wo = (const float*)d_in[4];
  const float* bo = (const float*)d_in[5];
  float* out = (float*)d_out;
  unsigned short* ws = (unsigned short*)d_ws;

  const size_t SZ = (size_t)MR * DD;         // 4096*1024

  // ws: [0] Q (ctx in-place)  [1] K  [2] Vt[b][h][d][t]  [3] Wb  [4] xb (opt)
  unsigned short* Qb  = ws;
  unsigned short* Kbf = ws + SZ;
  unsigned short* Vt  = ws + 2 * SZ;
  unsigned short* Wb  = ws + 3 * SZ;
  unsigned short* xb  = ws + 4 * SZ;

  const bool fast = ws_size >= 5 * SZ * sizeof(unsigned short);

  cvt_all<<<dim3(fast ? 4096 : 2048), 256, 0, stream>>>(Wq, Wk, Wv, Wo, x, Wb, xb);
  if (fast)
    gemm_qkv<true><<<dim3(32, 24), 256, 0, stream>>>(x, xb, Wb, Qb, Kbf, Vt);
  else
    gemm_qkv<false><<<dim3(32, 24), 256, 0, stream>>>(x, xb, Wb, Qb, Kbf, Vt);
  attn<<<dim3(2 * NH * 16), 256, 0, stream>>>(Qb, Kbf, Vt, Qb);
  gemm_out<<<dim3(32, 8), 256, 0, stream>>>(Qb, Wb + 3 * (size_t)DD * DD, bo, out);
}

// Round 10
// 197.270 us; speedup vs baseline: 2.1055x; 1.0006x over previous
//
#include <hip/hip_runtime.h>

// Problem constants
#define TT 2048
#define DD 1024
#define NH 16
#define DH 64
#define MR 4096            // B*T rows

typedef __attribute__((ext_vector_type(8))) short bf16x8;
typedef __attribute__((ext_vector_type(4))) short bf16x4;
typedef __attribute__((ext_vector_type(4))) float f32x4;
typedef __attribute__((ext_vector_type(2))) unsigned int u32x2;

__device__ __forceinline__ float bf2f(unsigned short u) {
  unsigned int x = ((unsigned int)u) << 16;
  return __builtin_bit_cast(float, x);
}
__device__ __forceinline__ unsigned short f2bf(float f) {
  unsigned int x = __builtin_bit_cast(unsigned int, f);
  x = (x + 0x7fffu + ((x >> 16) & 1u)) >> 16;
  return (unsigned short)x;
}
// Pack two fp32 -> packed bf16 pair (single v_cvt_pk_bf16_f32 on gfx950).
__device__ __forceinline__ unsigned int pack_bf2(float a, float b) {
#if __has_builtin(__builtin_amdgcn_cvt_pk_bf16_f32)
  typedef __attribute__((ext_vector_type(2))) __bf16 bf2_t;
  bf2_t v = __builtin_amdgcn_cvt_pk_bf16_f32(a, b);
  return __builtin_bit_cast(unsigned int, v);
#else
  return (unsigned int)f2bf(a) | ((unsigned int)f2bf(b) << 16);
#endif
}
__device__ __forceinline__ bf16x8 load8(const float* p) {
  bf16x8 r;
#pragma unroll
  for (int e = 0; e < 8; ++e) r[e] = (short)f2bf(p[e]);
  return r;
}

// K=16 bf16 MFMA (A/B = 4 bf16 in 2 VGPRs). Sᵀ C-layout == its A-layout.
#if __has_builtin(__builtin_amdgcn_mfma_f32_16x16x16_bf16)
#define MFMA_K16(A, B, C) __builtin_amdgcn_mfma_f32_16x16x16_bf16(A, B, C, 0, 0, 0)
#else
#define MFMA_K16(A, B, C) __builtin_amdgcn_mfma_f32_16x16x16bf16_1k(A, B, C, 0, 0, 0)
#endif

// Async global->LDS 16B/lane; LDS base wave-uniform, HW adds lane*16.
__device__ __forceinline__ void stage16(const unsigned short* g,
                                        unsigned short* lbase, int lane) {
#if __has_builtin(__builtin_amdgcn_global_load_lds)
  __builtin_amdgcn_global_load_lds(
      (const __attribute__((address_space(1))) unsigned int*)g,
      (__attribute__((address_space(3))) unsigned int*)(lbase + lane * 8),
      16, 0, 0);
#else
  *(bf16x8*)(lbase + lane * 8) = *(const bf16x8*)g;
#endif
}

// ---------------------------------------------------------------------------
// Convert: Wb rows = [Wk; Wq; Wv; Wo] (reference Q/K swap!); blocks >= 2048
// additionally convert x -> xb (linear). Fallback mode launches 2048 blocks.
// ---------------------------------------------------------------------------
__global__ __launch_bounds__(256) void cvt_all(
    const float* __restrict__ Wq, const float* __restrict__ Wk,
    const float* __restrict__ Wv, const float* __restrict__ Wo,
    const float* __restrict__ x,
    unsigned short* __restrict__ Wb, unsigned short* __restrict__ xb)
{
  int c = blockIdx.x * 256 + threadIdx.x;     // chunk of 8 elems
  if (c < 524288) {
    int idx = c * 8, n = idx >> 10, col = idx & 1023;
    const float* src = (n < 1024) ? Wk + (size_t)n * 1024
                     : (n < 2048) ? Wq + (size_t)(n - 1024) * 1024
                     : (n < 3072) ? Wv + (size_t)(n - 2048) * 1024
                                  : Wo + (size_t)(n - 3072) * 1024;
    *(bf16x8*)&Wb[idx] = load8(src + col);
  } else {
    size_t idx = (size_t)(c - 524288) * 8;
    *(bf16x8*)&xb[idx] = load8(&x[idx]);
  }
}

// ---------------------------------------------------------------------------
// Fused QKV projection: x[4096][1024] · Wb[0:3072]^T -> Q | K | Vt.
// 128x128 tile, BK=32, XOR-swizzled LDS, async staging for B (and A if FAST).
// V written TRANSPOSED to Vt[b][h][d][t] via LDS-transposed epilogue.
// ---------------------------------------------------------------------------
template <bool FAST>
__global__ __launch_bounds__(256) void gemm_qkv(
    const float* __restrict__ x, const unsigned short* __restrict__ xb,
    const unsigned short* __restrict__ Wb,
    unsigned short* __restrict__ Q, unsigned short* __restrict__ Kb,
    unsigned short* __restrict__ Vt)
{
  __shared__ unsigned short pool[8704];      // As(4096)+Bs(4096) | Tt(8704)
  unsigned short* As = pool;
  unsigned short* Bs = pool + 4096;

  const int tid = threadIdx.x, wave = tid >> 6, lane = tid & 63;
  const int lr = lane & 15, quad = lane >> 4;
  const int bm = blockIdx.x * 128, bn = blockIdx.y * 128;
  const int wm = (wave >> 1) * 64, wn = (wave & 1) * 64;

  f32x4 acc[4][4] = {};

  for (int k0 = 0; k0 < 1024; k0 += 32) {
#pragma unroll
    for (int i = 0; i < 2; ++i) {
      int c = wave * 128 + i * 64 + lane;    // chunk 0..511
      int row = c >> 2, l8 = (c & 3) ^ ((row >> 1) & 3);
      stage16(&Wb[(size_t)(bn + row) * 1024 + k0 + l8 * 8],
              &Bs[(wave * 2 + i) * 512], lane);
      if constexpr (FAST)
        stage16(&xb[(size_t)(bm + row) * 1024 + k0 + l8 * 8],
                &As[(wave * 2 + i) * 512], lane);
    }
    if constexpr (!FAST) {
#pragma unroll
      for (int i = 0; i < 2; ++i) {
        int c = tid + i * 256;
        int row = c >> 2, l8 = c & 3, p8 = l8 ^ ((row >> 1) & 3);
        *(bf16x8*)&As[row * 32 + p8 * 8] =
            load8(&x[(size_t)(bm + row) * 1024 + k0 + l8 * 8]);
      }
    }
    __syncthreads();

    bf16x8 af[4], bf[4];
#pragma unroll
    for (int mt = 0; mt < 4; ++mt) {
      int row = wm + mt * 16 + lr;
      af[mt] = *(const bf16x8*)&As[row * 32 + (quad ^ ((row >> 1) & 3)) * 8];
    }
#pragma unroll
    for (int nt = 0; nt < 4; ++nt) {
      int row = wn + nt * 16 + lr;
      bf[nt] = *(const bf16x8*)&Bs[row * 32 + (quad ^ ((row >> 1) & 3)) * 8];
    }
#pragma unroll
    for (int mt = 0; mt < 4; ++mt)
#pragma unroll
      for (int nt = 0; nt < 4; ++nt)
        acc[mt][nt] = __builtin_amdgcn_mfma_f32_16x16x32_bf16(
            af[mt], bf[nt], acc[mt][nt], 0, 0, 0);
    __syncthreads();
  }

  if (bn < 2048) {
    unsigned short* Cp = (bn < 1024) ? Q : Kb;
    int coff = (bn < 1024) ? bn : bn - 1024;
#pragma unroll
    for (int nt = 0; nt < 4; ++nt) {
      int col = coff + wn + nt * 16 + lr;
#pragma unroll
      for (int mt = 0; mt < 4; ++mt) {
        int row = bm + wm + mt * 16 + quad * 4;
#pragma unroll
        for (int r = 0; r < 4; ++r)
          Cp[(size_t)(row + r) * 1024 + col] = f2bf(acc[mt][nt][r]);
      }
    }
  } else {
    const int b = bm >> 11, t0 = bm & 2047, d0 = bn - 2048;
    unsigned short* Tt = pool;               // [64][136]
#pragma unroll
    for (int hv = 0; hv < 2; ++hv) {
      __syncthreads();
      if ((wave & 1) == hv) {
#pragma unroll
        for (int nt = 0; nt < 4; ++nt)
#pragma unroll
          for (int mt = 0; mt < 4; ++mt)
#pragma unroll
            for (int r = 0; r < 4; ++r)
              Tt[(nt * 16 + lr) * 136 + wm + mt * 16 + quad * 4 + r] =
                  f2bf(acc[mt][nt][r]);
      }
      __syncthreads();
#pragma unroll
      for (int ch = 0; ch < 4; ++ch) {
        int cc = tid + ch * 256;
        int d64 = cc >> 4, t8 = cc & 15;
        int dg = d0 + hv * 64 + d64;
        int h = dg >> 6, d = dg & 63;
        bf16x8 v = *(const bf16x8*)&Tt[d64 * 136 + t8 * 8];
        *(bf16x8*)&Vt[(((size_t)(b * NH + h) * 64 + d) << 11) + t0 + t8 * 8] = v;
      }
    }
  }
}

// ---------------------------------------------------------------------------
// Flash attention v4: Sᵀ formulation + complementary pairing + async staging
// + VALU diet: P packed via v_cvt_pk_bf16_f32, and the softmax denominator l
// accumulated as a 5th PV output with a constant-ones B fragment (same
// recurrence as O: l = l*alpha + sum(P)), killing the 32-add + shfl reduce
// and the epilogue l-shfls (ones-output C-layout broadcasts l to all lanes).
// ---------------------------------------------------------------------------
__global__ __launch_bounds__(256) void attn(
    const unsigned short* __restrict__ Q,
    const unsigned short* __restrict__ Kb,
    const unsigned short* __restrict__ Vt,
    unsigned short* __restrict__ ctx)
{
  __shared__ unsigned short Ks[128 * 64];    // [kseq][d]   8 chunks/row
  __shared__ unsigned short Vs[64 * 128];    // [d][t]     16 chunks/row

  const int tid = threadIdx.x, wave = tid >> 6, lane = tid & 63;
  const int lr = lane & 15, quad = lane >> 4;
  const int p = blockIdx.x & 15;
  const int h = (blockIdx.x >> 4) & 15;
  const int b = blockIdx.x >> 8;

  const size_t qkbase = ((size_t)b * TT) * 1024 + h * 64;
  const size_t vbase  = ((size_t)(b * NH + h) * 64) << 11;
  const float QS = 0.125f * 1.44269504f;     // scale * log2(e)

  bf16x4 ones;
#pragma unroll
  for (int e = 0; e < 4; ++e) ones[e] = (short)0x3F80;   // bf16 1.0

#pragma unroll
  for (int pass = 0; pass < 2; ++pass) {
    const int qt = pass ? p : (31 - p);
    const int qrow0 = qt * 64 + wave * 16;
    const int qrow  = qrow0 + lr;

    // Q fragment (B-operand), pre-scaled
    bf16x8 qf[2];
#pragma unroll
    for (int kb = 0; kb < 2; ++kb) {
      bf16x8 raw = *(const bf16x8*)&Q[qkbase + (size_t)(qrow0 + lr) * 1024 + kb * 32 + quad * 8];
#pragma unroll
      for (int e = 0; e < 8; ++e)
        qf[kb][e] = (short)f2bf(bf2f((unsigned short)raw[e]) * QS);
    }

    float m_i = -1e30f;
    f32x4 od[4] = {};                        // O[m=quad*4+r][d=dt*16+lr]
    f32x4 ol = {};                           // l[m=quad*4+r] (all lanes)
    const int jmax = qt >> 1;

    for (int j = 0; j <= jmax; ++j) {
      // async stage K [128][64]: wave stages 4 x 1KB, source-swizzled
#pragma unroll
      for (int i = 0; i < 4; ++i) {
        int ci = (wave * 4 + i) * 64 + lane;       // phys chunk 0..1023
        int row = ci >> 3, lc = (ci & 7) ^ (row & 7);
        stage16(&Kb[qkbase + (size_t)(j * 128 + row) * 1024 + lc * 8],
                &Ks[(wave * 4 + i) * 512], lane);
      }
      // async stage V [64][128] from pre-transposed Vt
#pragma unroll
      for (int i = 0; i < 4; ++i) {
        int ci = (wave * 4 + i) * 64 + lane;
        int d = ci >> 4, lc = (ci & 15) ^ (d & 15);
        stage16(&Vt[vbase + ((size_t)d << 11) + j * 128 + lc * 8],
                &Vs[(wave * 4 + i) * 512], lane);
      }
      __syncthreads();

      const bool diag = (j == jmax);
      const int nlim = (diag && !(qt & 1)) ? 4 : 8;  // skip fully-masked half

      // S^T = K·Qᵀ: C col(lr)=q-row, row(quad*4+r)=k-pos
      f32x4 s[8];
#pragma unroll
      for (int nt = 0; nt < 8; ++nt)
        if (nt < nlim) {
          f32x4 a = {0.f, 0.f, 0.f, 0.f};
#pragma unroll
          for (int kb = 0; kb < 2; ++kb) {
            int pc = (kb * 4 + quad) ^ (lr & 7);
            bf16x8 kf = *(const bf16x8*)&Ks[(nt * 16 + lr) * 64 + pc * 8];
            a = __builtin_amdgcn_mfma_f32_16x16x32_bf16(kf, qf[kb], a, 0, 0, 0);
          }
          s[nt] = a;
        }

      // causal mask (diag tile only)
      if (diag) {
#pragma unroll
        for (int nt = 0; nt < 8; ++nt)
          if (nt < nlim)
#pragma unroll
            for (int r = 0; r < 4; ++r) {
              int kpos = j * 128 + nt * 16 + quad * 4 + r;
              if (kpos > qrow) s[nt][r] = -1e30f;
            }
      }

      // running max: per-lane register reduction + 2 cross-quad shfls
      float mloc = -1e30f;
#pragma unroll
      for (int nt = 0; nt < 8; ++nt)
        if (nt < nlim)
#pragma unroll
          for (int r = 0; r < 4; ++r) mloc = fmaxf(mloc, s[nt][r]);
      mloc = fmaxf(mloc, __shfl_xor(mloc, 16, 64));
      mloc = fmaxf(mloc, __shfl_xor(mloc, 32, 64));
      float mnew = fmaxf(m_i, mloc);
      float alpha = exp2f(m_i - mnew);
      m_i = mnew;

      // P = exp2(s - mnew), packed pairwise (v_cvt_pk_bf16_f32)
      bf16x4 pk[8];
#pragma unroll
      for (int nt = 0; nt < 8; ++nt)
        if (nt < nlim) {
          float p0 = exp2f(s[nt][0] - mnew), p1 = exp2f(s[nt][1] - mnew);
          float p2 = exp2f(s[nt][2] - mnew), p3 = exp2f(s[nt][3] - mnew);
          u32x2 u = {pack_bf2(p0, p1), pack_bf2(p2, p3)};
          pk[nt] = __builtin_bit_cast(bf16x4, u);
        }

      // rescale O and l: alpha for row quad*4+r lives at lane lr==row
      float am[4];
#pragma unroll
      for (int r = 0; r < 4; ++r) am[r] = __shfl(alpha, quad * 4 + r, 16);
#pragma unroll
      for (int dt = 0; dt < 4; ++dt)
#pragma unroll
        for (int r = 0; r < 4; ++r) od[dt][r] *= am[r];
#pragma unroll
      for (int r = 0; r < 4; ++r) ol[r] *= am[r];

      // O += P·V, l += P·1  (K=16 MFMAs)
#pragma unroll
      for (int nt = 0; nt < 8; ++nt)
        if (nt < nlim) {
#pragma unroll
          for (int dt = 0; dt < 4; ++dt) {
            int pc = (nt * 2 + (quad >> 1)) ^ lr;
            bf16x4 vf = *(const bf16x4*)&Vs[(dt * 16 + lr) * 128 + pc * 8 + (quad & 1) * 4];
            od[dt] = MFMA_K16(pk[nt], vf, od[dt]);
          }
          ol = MFMA_K16(pk[nt], ones, ol);
        }
      __syncthreads();   // Ks/Vs rewritten next iter (or next pass)
    }

    // epilogue: O / l; l for row quad*4+r is ol[r] in every lane (ones-cols
    // are all identical). ctx aliases Q safely (qf loaded before store).
#pragma unroll
    for (int dt = 0; dt < 4; ++dt) {
      int col = h * 64 + dt * 16 + lr;
#pragma unroll
      for (int r = 0; r < 4; ++r) {
        int row = qrow0 + quad * 4 + r;
        ctx[((size_t)b * TT + row) * 1024 + col] = f2bf(od[dt][r] / ol[r]);
      }
    }
  }
}

// ---------------------------------------------------------------------------
// Output projection: ctx(bf16) · Wo(bf16)^T + bo -> fp32 out.
// ---------------------------------------------------------------------------
__global__ __launch_bounds__(256) void gemm_out(
    const unsigned short* __restrict__ A,
    const unsigned short* __restrict__ Bw,
    const float* __restrict__ bias,
    float* __restrict__ out)
{
  __shared__ unsigned short pool[8192];
  unsigned short* As = pool;
  unsigned short* Bs = pool + 4096;

  const int tid = threadIdx.x, wave = tid >> 6, lane = tid & 63;
  const int lr = lane & 15, quad = lane >> 4;
  const int bm = blockIdx.x * 128, bn = blockIdx.y * 128;
  const int wm = (wave >> 1) * 64, wn = (wave & 1) * 64;

  f32x4 acc[4][4] = {};

  for (int k0 = 0; k0 < 1024; k0 += 32) {
#pragma unroll
    for (int i = 0; i < 2; ++i) {
      int c = wave * 128 + i * 64 + lane;
      int row = c >> 2, l8 = (c & 3) ^ ((row >> 1) & 3);
      stage16(&A[(size_t)(bm + row) * 1024 + k0 + l8 * 8],
              &As[(wave * 2 + i) * 512], lane);
      stage16(&Bw[(size_t)(bn + row) * 1024 + k0 + l8 * 8],
              &Bs[(wave * 2 + i) * 512], lane);
    }
    __syncthreads();

    bf16x8 af[4], bf[4];
#pragma unroll
    for (int mt = 0; mt < 4; ++mt) {
      int row = wm + mt * 16 + lr;
      af[mt] = *(const bf16x8*)&As[row * 32 + (quad ^ ((row >> 1) & 3)) * 8];
    }
#pragma unroll
    for (int nt = 0; nt < 4; ++nt) {
      int row = wn + nt * 16 + lr;
      bf[nt] = *(const bf16x8*)&Bs[row * 32 + (quad ^ ((row >> 1) & 3)) * 8];
    }
#pragma unroll
    for (int mt = 0; mt < 4; ++mt)
#pragma unroll
      for (int nt = 0; nt < 4; ++nt)
        acc[mt][nt] = __builtin_amdgcn_mfma_f32_16x16x32_bf16(
            af[mt], bf[nt], acc[mt][nt], 0, 0, 0);
    __syncthreads();
  }

#pragma unroll
  for (int nt = 0; nt < 4; ++nt) {
    int col = bn + wn + nt * 16 + lr;
    float bv = bias[col];
#pragma unroll
    for (int mt = 0; mt < 4; ++mt) {
      int row = bm + wm + mt * 16 + quad * 4;
#pragma unroll
      for (int r = 0; r < 4; ++r)
        out[(size_t)(row + r) * 1024 + col] = acc[mt][nt][r] + bv;
    }
  }
}

// ---------------------------------------------------------------------------
extern "C" void kernel_launch(void* const* d_in, const int* in_sizes, int n_in,
                              void* d_out, int out_size, void* d_ws, size_t ws_size,
                              hipStream_t stream) {
  const float* x  = (const float*)d_in[0];
  const float* Wq = (const float*)d_in[1];
  const float* Wk = (const float*)d_in[2];
  const float* Wv = (const float*)d_in[3];
  const float* Wo = (const float*)d_in[4];
  const float* bo = (const float*)d_in[5];
  float* out = (float*)d_out;
  unsigned short* ws = (unsigned short*)d_ws;

  const size_t SZ = (size_t)MR * DD;         // 4096*1024

  // ws: [0] Q (ctx in-place)  [1] K  [2] Vt[b][h][d][t]  [3] Wb  [4] xb (opt)
  unsigned short* Qb  = ws;
  unsigned short* Kbf = ws + SZ;
  unsigned short* Vt  = ws + 2 * SZ;
  unsigned short* Wb  = ws + 3 * SZ;
  unsigned short* xb  = ws + 4 * SZ;

  const bool fast = ws_size >= 5 * SZ * sizeof(unsigned short);

  cvt_all<<<dim3(fast ? 4096 : 2048), 256, 0, stream>>>(Wq, Wk, Wv, Wo, x, Wb, xb);
  if (fast)
    gemm_qkv<true><<<dim3(32, 24), 256, 0, stream>>>(x, xb, Wb, Qb, Kbf, Vt);
  else
    gemm_qkv<false><<<dim3(32, 24), 256, 0, stream>>>(x, xb, Wb, Qb, Kbf, Vt);
  attn<<<dim3(2 * NH * 16), 256, 0, stream>>>(Qb, Kbf, Vt, Qb);
  gemm_out<<<dim3(32, 8), 256, 0, stream>>>(Qb, Wb + 3 * (size_t)DD * DD, bo, out);
}